// Round 5
// baseline (6778.197 us; speedup 1.0000x reference)
//
#include <hip/hip_runtime.h>

// B=4, Cin=Cout=64, H=W=128, K=9, PAD=1. NCHW fp32 in/out.
// Einsum via split-bf16 MFMA: x = hi + lo (both bf16);
// A*B ~= Ah*Bh + Ah*Bl + Al*Bh  (error ~2^-17, ~fp32).
//
// GEMM view per layer:  C[64 o, 65536 px] = W[64 o, 576 ck] * S[576 ck, px]
// ck k-major: chunk = k*2 + chalf, 32 c per chunk, 18 chunks.
// Block: 64 o x 64 px tile, 4 waves; dcn wave = 16 o x 64 px (4 subtiles).

typedef __attribute__((ext_vector_type(8))) short short8;
typedef __attribute__((ext_vector_type(4))) float floatx4;

__device__ __forceinline__ unsigned short bf16r(float f) {
  unsigned u = __float_as_uint(f);
  u += 0x7FFF + ((u >> 16) & 1);
  return (unsigned short)(u >> 16);
}
__device__ __forceinline__ float bf2f(unsigned short h) {
  return __uint_as_float((unsigned)h << 16);
}

// ---------------- prep: pack hi/lo weights into MFMA A-frag order + BN ------
// wpk  [chunk 18][wave 4][part 2][lane 64][j 8]: o=wave*16+(lane&15),
//       c=(chunk&1)*32+(lane>>4)*8+j, k=chunk>>1
// wopk [chunk 18][ot 2][part 2][lane 64][j 8]:   o=ot*16+(lane&15) (0 if >=18)
__global__ __launch_bounds__(256) void prep_kernel(
    const float* __restrict__ w1, const float* __restrict__ w2,
    const float* __restrict__ woff1, const float* __restrict__ woff2,
    const float* __restrict__ g1, const float* __restrict__ be1,
    const float* __restrict__ m1, const float* __restrict__ v1,
    const float* __restrict__ g2, const float* __restrict__ be2,
    const float* __restrict__ m2, const float* __restrict__ v2,
    unsigned short* __restrict__ wpk1, unsigned short* __restrict__ wpk2,
    unsigned short* __restrict__ wopk1, unsigned short* __restrict__ wopk2,
    float* __restrict__ bn1, float* __restrict__ bn2) {
  int idx = blockIdx.x * 256 + threadIdx.x;
  if (idx < 147456) {
    int t = idx < 73728 ? idx : idx - 73728;
    const float* w = idx < 73728 ? w1 : w2;
    unsigned short* d = idx < 73728 ? wpk1 : wpk2;
    int j = t & 7, lane = (t >> 3) & 63, part = (t >> 9) & 1;
    int wv = (t >> 10) & 3, chunk = t >> 12;
    int k = chunk >> 1;
    int o = wv * 16 + (lane & 15);
    int c = (chunk & 1) * 32 + (lane >> 4) * 8 + j;
    float val = w[(o * 64 + c) * 9 + k];
    unsigned short hi = bf16r(val);
    d[t] = part ? bf16r(val - bf2f(hi)) : hi;
  } else if (idx < 221184) {
    int u = idx - 147456;
    int t = u < 36864 ? u : u - 36864;
    const float* w = u < 36864 ? woff1 : woff2;
    unsigned short* d = u < 36864 ? wopk1 : wopk2;
    int j = t & 7, lane = (t >> 3) & 63, part = (t >> 9) & 1;
    int ot = (t >> 10) & 1, chunk = t >> 11;
    int tt = chunk >> 1;
    int o = ot * 16 + (lane & 15);
    int c = (chunk & 1) * 32 + (lane >> 4) * 8 + j;
    float val = (o < 18) ? w[(o * 64 + c) * 9 + tt] : 0.f;
    unsigned short hi = bf16r(val);
    d[t] = part ? bf16r(val - bf2f(hi)) : hi;
  } else if (idx < 221248) {
    int o = idx - 221184;
    float s = g1[o] * rsqrtf(v1[o] + 1e-5f);
    bn1[o] = s; bn1[64 + o] = be1[o] - m1[o] * s;
  } else if (idx < 221312) {
    int o = idx - 221248;
    float s = g2[o] * rsqrtf(v2[o] + 1e-5f);
    bn2[o] = s; bn2[64 + o] = be2[o] - m2[o] * s;
  }
}

#define PACK_HILO(dst_h, dst_l, src_expr)                                  \
  {                                                                        \
    union { unsigned short us[8]; short8 v; } ph, plo;                     \
    _Pragma("unroll") for (int i = 0; i < 8; ++i) {                        \
      float sv_ = (src_expr);                                              \
      unsigned short h_ = bf16r(sv_);                                      \
      ph.us[i] = h_;                                                       \
      plo.us[i] = bf16r(sv_ - bf2f(h_));                                   \
    }                                                                      \
    *(short8*)(dst_h) = ph.v;                                              \
    *(short8*)(dst_l) = plo.v;                                             \
  }

// ---------------- offset conv via MFMA: 3x3, 64 -> 18 (padded 32) -----------
__global__ __launch_bounds__(256, 4) void conv_off_kernel(
    const float* __restrict__ xin, const unsigned short* __restrict__ wopk,
    const float* __restrict__ boff, float* __restrict__ off) {
  __shared__ __align__(16) unsigned short sb[2][2][64][40];  // [dbuf][part][px][c]
  int tid = threadIdx.x;
  int lane = tid & 63;
  int wave = tid >> 6;
  int px = lane;
  int crow = wave * 8;
  int p0 = blockIdx.x * 64;
  int b = p0 >> 14, hw0 = p0 & 16383;
  int h = hw0 >> 7, w0 = hw0 & 127;
  const float* xb = xin + ((size_t)b << 20);

  floatx4 acc0 = {0.f, 0.f, 0.f, 0.f}, acc1 = {0.f, 0.f, 0.f, 0.f};
  int sA = (wave >> 1) * 2;   // px-subtile pair
  int ot = wave & 1;          // o tile

  int ofs, ofsn; bool ok, okn;
  {
    int yy = h - 1, xx = w0 + px - 1;
    ok = (yy >= 0) & (xx >= 0);
    ofs = (max(yy, 0) << 7) + max(xx, 0);
  }
  float tp0[8], tp1[8];
#pragma unroll
  for (int i = 0; i < 8; ++i) {
    float v = xb[((size_t)(crow + i) << 14) + ofs];
    tp0[i] = ok ? v : 0.f;
  }

#pragma unroll 1
  for (int t = 0; t < 9; ++t) {
    {  // ---- chunk 2t (c 0..31) -> sb[0]
      PACK_HILO(&sb[0][0][px][crow], &sb[0][1][px][crow], tp0[i]);
#pragma unroll
      for (int i = 0; i < 8; ++i) {  // prefetch c 32..63, same tap
        float v = xb[((size_t)(32 + crow + i) << 14) + ofs];
        tp1[i] = ok ? v : 0.f;
      }
      if (t < 8) {
        int tn = t + 1;
        int yy = h + tn / 3 - 1, xx = w0 + px + tn % 3 - 1;
        okn = (yy >= 0) & (yy < 128) & (xx >= 0) & (xx < 128);
        ofsn = (min(max(yy, 0), 127) << 7) + min(max(xx, 0), 127);
      }
      __syncthreads();
      const unsigned short* ab = wopk + ((size_t)(2 * t) * 2 + ot) * 1024 + lane * 8;
      const short8 ah = *(const short8*)ab;
      const short8 al = *(const short8*)(ab + 512);
      short8 bh0 = *(const short8*)&sb[0][0][sA * 16 + (lane & 15)][(lane >> 4) * 8];
      short8 bl0 = *(const short8*)&sb[0][1][sA * 16 + (lane & 15)][(lane >> 4) * 8];
      acc0 = __builtin_amdgcn_mfma_f32_16x16x32_bf16(ah, bh0, acc0, 0, 0, 0);
      acc0 = __builtin_amdgcn_mfma_f32_16x16x32_bf16(ah, bl0, acc0, 0, 0, 0);
      acc0 = __builtin_amdgcn_mfma_f32_16x16x32_bf16(al, bh0, acc0, 0, 0, 0);
      short8 bh1 = *(const short8*)&sb[0][0][(sA + 1) * 16 + (lane & 15)][(lane >> 4) * 8];
      short8 bl1 = *(const short8*)&sb[0][1][(sA + 1) * 16 + (lane & 15)][(lane >> 4) * 8];
      acc1 = __builtin_amdgcn_mfma_f32_16x16x32_bf16(ah, bh1, acc1, 0, 0, 0);
      acc1 = __builtin_amdgcn_mfma_f32_16x16x32_bf16(ah, bl1, acc1, 0, 0, 0);
      acc1 = __builtin_amdgcn_mfma_f32_16x16x32_bf16(al, bh1, acc1, 0, 0, 0);
    }
    {  // ---- chunk 2t+1 (c 32..63) -> sb[1]
      PACK_HILO(&sb[1][0][px][crow], &sb[1][1][px][crow], tp1[i]);
      if (t < 8) {
#pragma unroll
        for (int i = 0; i < 8; ++i) {  // prefetch next tap, c 0..31
          float v = xb[((size_t)(crow + i) << 14) + ofsn];
          tp0[i] = okn ? v : 0.f;
        }
      }
      __syncthreads();
      const unsigned short* ab = wopk + ((size_t)(2 * t + 1) * 2 + ot) * 1024 + lane * 8;
      const short8 ah = *(const short8*)ab;
      const short8 al = *(const short8*)(ab + 512);
      short8 bh0 = *(const short8*)&sb[1][0][sA * 16 + (lane & 15)][(lane >> 4) * 8];
      short8 bl0 = *(const short8*)&sb[1][1][sA * 16 + (lane & 15)][(lane >> 4) * 8];
      acc0 = __builtin_amdgcn_mfma_f32_16x16x32_bf16(ah, bh0, acc0, 0, 0, 0);
      acc0 = __builtin_amdgcn_mfma_f32_16x16x32_bf16(ah, bl0, acc0, 0, 0, 0);
      acc0 = __builtin_amdgcn_mfma_f32_16x16x32_bf16(al, bh0, acc0, 0, 0, 0);
      short8 bh1 = *(const short8*)&sb[1][0][(sA + 1) * 16 + (lane & 15)][(lane >> 4) * 8];
      short8 bl1 = *(const short8*)&sb[1][1][(sA + 1) * 16 + (lane & 15)][(lane >> 4) * 8];
      acc1 = __builtin_amdgcn_mfma_f32_16x16x32_bf16(ah, bh1, acc1, 0, 0, 0);
      acc1 = __builtin_amdgcn_mfma_f32_16x16x32_bf16(ah, bl1, acc1, 0, 0, 0);
      acc1 = __builtin_amdgcn_mfma_f32_16x16x32_bf16(al, bh1, acc1, 0, 0, 0);
      ofs = ofsn; ok = okn;
    }
  }
  int q = lane >> 4, nn = lane & 15;
#pragma unroll
  for (int si = 0; si < 2; ++si) {
    floatx4 a = si ? acc1 : acc0;
    int pxc = (sA + si) * 16 + nn;
#pragma unroll
    for (int r = 0; r < 4; ++r) {
      int o = ot * 16 + q * 4 + r;
      if (o < 18)
        off[((size_t)(b * 18 + o) << 14) + hw0 + pxc] = a[r] + boff[o];
    }
  }
}

// ---------------- dcn: sample -> split-bf16 S in LDS -> MFMA -> BN+ReLU -----
__global__ __launch_bounds__(256, 4) void dcn_main_kernel(
    const float* __restrict__ xin, const float* __restrict__ off,
    const unsigned short* __restrict__ wpk, const float* __restrict__ bn,
    float* __restrict__ out) {
  __shared__ __align__(16) unsigned short sb[2][2][64][40];
  int tid = threadIdx.x;
  int lane = tid & 63;
  int wave = tid >> 6;
  int px = lane;
  int crow = wave * 8;
  int p0 = blockIdx.x * 64;
  int b = p0 >> 14, hw0 = p0 & 16383;
  int h = hw0 >> 7, w0 = hw0 & 127;
  const float* xb = xin + ((size_t)b << 20);

  floatx4 acc[4] = {{0.f,0.f,0.f,0.f},{0.f,0.f,0.f,0.f},{0.f,0.f,0.f,0.f},{0.f,0.f,0.f,0.f}};

  float pw[4], pwn[4] = {0.f, 0.f, 0.f, 0.f};
  int pidx[4], pidxn[4] = {0, 0, 0, 0};

  auto prm_math = [&](int k, float dy, float dx, float* w4, int* i4) {
    float py = (float)(h + k / 3 - 1) + dy;
    float pxf = (float)(w0 + px + (k % 3) - 1) + dx;
    float y0f = floorf(py), x0f = floorf(pxf);
    float wy1 = py - y0f, wx1 = pxf - x0f;
    float wy0 = 1.f - wy1, wx0 = 1.f - wx1;
    int y0 = (int)y0f, x0 = (int)x0f;
    int y1 = y0 + 1, x1 = x0 + 1;
    bool vy0 = (y0 >= 0) && (y0 <= 127);
    bool vy1 = (y1 >= 0) && (y1 <= 127);
    bool vx0 = (x0 >= 0) && (x0 <= 127);
    bool vx1 = (x1 >= 0) && (x1 <= 127);
    w4[0] = (vy0 && vx0) ? wy0 * wx0 : 0.f;
    w4[1] = (vy0 && vx1) ? wy0 * wx1 : 0.f;
    w4[2] = (vy1 && vx0) ? wy1 * wx0 : 0.f;
    w4[3] = (vy1 && vx1) ? wy1 * wx1 : 0.f;
    int y0c = min(max(y0, 0), 127), y1c = min(max(y1, 0), 127);
    int x0c = min(max(x0, 0), 127), x1c = min(max(x1, 0), 127);
    i4[0] = (y0c << 7) + x0c;
    i4[1] = (y0c << 7) + x1c;
    i4[2] = (y1c << 7) + x0c;
    i4[3] = (y1c << 7) + x1c;
  };

  {
    float dy = off[((size_t)(b * 18 + 0) << 14) + hw0 + px];
    float dx = off[((size_t)(b * 18 + 1) << 14) + hw0 + px];
    prm_math(0, dy, dx, pw, pidx);
  }
  float tp0[32], tp1[32];
#pragma unroll
  for (int i = 0; i < 8; ++i) {
    const float* xp = xb + ((size_t)(crow + i) << 14);
    tp0[i * 4 + 0] = xp[pidx[0]]; tp0[i * 4 + 1] = xp[pidx[1]];
    tp0[i * 4 + 2] = xp[pidx[2]]; tp0[i * 4 + 3] = xp[pidx[3]];
  }

#pragma unroll 1
  for (int k = 0; k < 9; ++k) {
    float dyn = 0.f, dxn = 0.f;
    {  // ---- chunk 2k (c 0..31) -> sb[0]
      if (k < 8) {
        dyn = off[((size_t)(b * 18 + 2 * k + 2) << 14) + hw0 + px];
        dxn = off[((size_t)(b * 18 + 2 * k + 3) << 14) + hw0 + px];
      }
      PACK_HILO(&sb[0][0][px][crow], &sb[0][1][px][crow],
                fmaf(pw[0], tp0[i * 4], fmaf(pw[1], tp0[i * 4 + 1],
                fmaf(pw[2], tp0[i * 4 + 2], pw[3] * tp0[i * 4 + 3]))));
#pragma unroll
      for (int i = 0; i < 8; ++i) {  // prefetch c 32..63, same k
        const float* xp = xb + ((size_t)(32 + crow + i) << 14);
        tp1[i * 4 + 0] = xp[pidx[0]]; tp1[i * 4 + 1] = xp[pidx[1]];
        tp1[i * 4 + 2] = xp[pidx[2]]; tp1[i * 4 + 3] = xp[pidx[3]];
      }
      __syncthreads();
      const unsigned short* ab = wpk + ((size_t)(2 * k) * 4 + wave) * 1024 + lane * 8;
      const short8 ah = *(const short8*)ab;
      const short8 al = *(const short8*)(ab + 512);
#pragma unroll
      for (int s4 = 0; s4 < 4; ++s4) {
        short8 bh = *(const short8*)&sb[0][0][s4 * 16 + (lane & 15)][(lane >> 4) * 8];
        short8 bl = *(const short8*)&sb[0][1][s4 * 16 + (lane & 15)][(lane >> 4) * 8];
        acc[s4] = __builtin_amdgcn_mfma_f32_16x16x32_bf16(ah, bh, acc[s4], 0, 0, 0);
        acc[s4] = __builtin_amdgcn_mfma_f32_16x16x32_bf16(ah, bl, acc[s4], 0, 0, 0);
        acc[s4] = __builtin_amdgcn_mfma_f32_16x16x32_bf16(al, bh, acc[s4], 0, 0, 0);
      }
    }
    {  // ---- chunk 2k+1 (c 32..63) -> sb[1]
      if (k < 8) prm_math(k + 1, dyn, dxn, pwn, pidxn);
      PACK_HILO(&sb[1][0][px][crow], &sb[1][1][px][crow],
                fmaf(pw[0], tp1[i * 4], fmaf(pw[1], tp1[i * 4 + 1],
                fmaf(pw[2], tp1[i * 4 + 2], pw[3] * tp1[i * 4 + 3]))));
      if (k < 8) {
#pragma unroll
        for (int i = 0; i < 8; ++i) {  // prefetch next k, c 0..31
          const float* xp = xb + ((size_t)(crow + i) << 14);
          tp0[i * 4 + 0] = xp[pidxn[0]]; tp0[i * 4 + 1] = xp[pidxn[1]];
          tp0[i * 4 + 2] = xp[pidxn[2]]; tp0[i * 4 + 3] = xp[pidxn[3]];
        }
      }
      __syncthreads();
      const unsigned short* ab = wpk + ((size_t)(2 * k + 1) * 4 + wave) * 1024 + lane * 8;
      const short8 ah = *(const short8*)ab;
      const short8 al = *(const short8*)(ab + 512);
#pragma unroll
      for (int s4 = 0; s4 < 4; ++s4) {
        short8 bh = *(const short8*)&sb[1][0][s4 * 16 + (lane & 15)][(lane >> 4) * 8];
        short8 bl = *(const short8*)&sb[1][1][s4 * 16 + (lane & 15)][(lane >> 4) * 8];
        acc[s4] = __builtin_amdgcn_mfma_f32_16x16x32_bf16(ah, bh, acc[s4], 0, 0, 0);
        acc[s4] = __builtin_amdgcn_mfma_f32_16x16x32_bf16(ah, bl, acc[s4], 0, 0, 0);
        acc[s4] = __builtin_amdgcn_mfma_f32_16x16x32_bf16(al, bh, acc[s4], 0, 0, 0);
      }
#pragma unroll
      for (int qq = 0; qq < 4; ++qq) { pw[qq] = pwn[qq]; pidx[qq] = pidxn[qq]; }
    }
  }
  // epilogue: C/D frag row=(lane>>4)*4+r (o), col=lane&15 (px)
  int q = lane >> 4, nn = lane & 15;
#pragma unroll
  for (int s4 = 0; s4 < 4; ++s4) {
#pragma unroll
    for (int r = 0; r < 4; ++r) {
      int o = wave * 16 + q * 4 + r;
      float val = fmaf(acc[s4][r], bn[o], bn[64 + o]);
      out[((size_t)(b * 64 + o) << 14) + hw0 + s4 * 16 + nn] = fmaxf(val, 0.f);
    }
  }
}

extern "C" void kernel_launch(void* const* d_in, const int* in_sizes, int n_in,
                              void* d_out, int out_size, void* d_ws, size_t ws_size,
                              hipStream_t stream) {
  const float* x      = (const float*)d_in[0];
  const float* w_off1 = (const float*)d_in[1];
  const float* b_off1 = (const float*)d_in[2];
  const float* w1     = (const float*)d_in[3];
  const float* g1     = (const float*)d_in[4];
  const float* be1    = (const float*)d_in[5];
  const float* m1     = (const float*)d_in[6];
  const float* v1     = (const float*)d_in[7];
  const float* w_off2 = (const float*)d_in[8];
  const float* b_off2 = (const float*)d_in[9];
  const float* w2     = (const float*)d_in[10];
  const float* g2     = (const float*)d_in[11];
  const float* be2    = (const float*)d_in[12];
  const float* m2     = (const float*)d_in[13];
  const float* v2     = (const float*)d_in[14];
  float* out = (float*)d_out;

  unsigned short* wpk1  = (unsigned short*)d_ws;          // 73728
  unsigned short* wpk2  = wpk1 + 73728;                   // 73728
  unsigned short* wopk1 = wpk2 + 73728;                   // 36864
  unsigned short* wopk2 = wopk1 + 36864;                  // 36864
  float* bn1  = (float*)(wopk2 + 36864);                  // 128
  float* bn2  = bn1 + 128;                                // 128
  float* offb = bn2 + 128;                                // 4*18*16384
  float* hbuf = offb + 4 * 18 * 16384;                    // 4*64*16384

  prep_kernel<<<865, 256, 0, stream>>>(w1, w2, w_off1, w_off2,
                                       g1, be1, m1, v1, g2, be2, m2, v2,
                                       wpk1, wpk2, wopk1, wopk2, bn1, bn2);

  conv_off_kernel<<<1024, 256, 0, stream>>>(x, wopk1, b_off1, offb);
  dcn_main_kernel<<<1024, 256, 0, stream>>>(x, offb, wpk1, bn1, hbuf);

  conv_off_kernel<<<1024, 256, 0, stream>>>(hbuf, wopk2, b_off2, offb);
  dcn_main_kernel<<<1024, 256, 0, stream>>>(hbuf, offb, wpk2, bn2, out);
}

// Round 6
// 439.676 us; speedup vs baseline: 15.4163x; 15.4163x over previous
//
#include <hip/hip_runtime.h>

// B=4, Cin=Cout=64, H=W=128, K=9, PAD=1. NCHW fp32 in/out.
// Einsum via split-bf16 MFMA: x = hi + lo (both bf16);
// A*B ~= Ah*Bh + Ah*Bl + Al*Bh  (error ~2^-17, ~fp32).
//
// GEMM view per layer:  C[64 o, 65536 px] = W[64 o, 576 ck] * S[576 ck, px]
// ck k-major: chunk = k*2 + chalf, 32 c per chunk, 18 chunks.
// dcn block: 64 o x 32 px tile, 4 waves; wave = 16 o x 32 px (2 subtiles).
// Per-thread state kept small (tp[16], acc[2][4]) to avoid scratch spills.

typedef __attribute__((ext_vector_type(8))) short short8;
typedef __attribute__((ext_vector_type(4))) short short4v;
typedef __attribute__((ext_vector_type(4))) float floatx4;

__device__ __forceinline__ unsigned short bf16r(float f) {
  unsigned u = __float_as_uint(f);
  u += 0x7FFF + ((u >> 16) & 1);
  return (unsigned short)(u >> 16);
}
__device__ __forceinline__ float bf2f(unsigned short h) {
  return __uint_as_float((unsigned)h << 16);
}

// ---------------- prep: pack hi/lo weights into MFMA A-frag order + BN ------
// wpk  [chunk 18][wave 4][part 2][lane 64][j 8]: o=wave*16+(lane&15),
//       c=(chunk&1)*32+(lane>>4)*8+j, k=chunk>>1
// wopk [chunk 18][ot 2][part 2][lane 64][j 8]:   o=ot*16+(lane&15) (0 if >=18)
__global__ __launch_bounds__(256) void prep_kernel(
    const float* __restrict__ w1, const float* __restrict__ w2,
    const float* __restrict__ woff1, const float* __restrict__ woff2,
    const float* __restrict__ g1, const float* __restrict__ be1,
    const float* __restrict__ m1, const float* __restrict__ v1,
    const float* __restrict__ g2, const float* __restrict__ be2,
    const float* __restrict__ m2, const float* __restrict__ v2,
    unsigned short* __restrict__ wpk1, unsigned short* __restrict__ wpk2,
    unsigned short* __restrict__ wopk1, unsigned short* __restrict__ wopk2,
    float* __restrict__ bn1, float* __restrict__ bn2) {
  int idx = blockIdx.x * 256 + threadIdx.x;
  if (idx < 147456) {
    int t = idx < 73728 ? idx : idx - 73728;
    const float* w = idx < 73728 ? w1 : w2;
    unsigned short* d = idx < 73728 ? wpk1 : wpk2;
    int j = t & 7, lane = (t >> 3) & 63, part = (t >> 9) & 1;
    int wv = (t >> 10) & 3, chunk = t >> 12;
    int k = chunk >> 1;
    int o = wv * 16 + (lane & 15);
    int c = (chunk & 1) * 32 + (lane >> 4) * 8 + j;
    float val = w[(o * 64 + c) * 9 + k];
    unsigned short hi = bf16r(val);
    d[t] = part ? bf16r(val - bf2f(hi)) : hi;
  } else if (idx < 221184) {
    int u = idx - 147456;
    int t = u < 36864 ? u : u - 36864;
    const float* w = u < 36864 ? woff1 : woff2;
    unsigned short* d = u < 36864 ? wopk1 : wopk2;
    int j = t & 7, lane = (t >> 3) & 63, part = (t >> 9) & 1;
    int ot = (t >> 10) & 1, chunk = t >> 11;
    int tt = chunk >> 1;
    int o = ot * 16 + (lane & 15);
    int c = (chunk & 1) * 32 + (lane >> 4) * 8 + j;
    float val = (o < 18) ? w[(o * 64 + c) * 9 + tt] : 0.f;
    unsigned short hi = bf16r(val);
    d[t] = part ? bf16r(val - bf2f(hi)) : hi;
  } else if (idx < 221248) {
    int o = idx - 221184;
    float s = g1[o] * rsqrtf(v1[o] + 1e-5f);
    bn1[o] = s; bn1[64 + o] = be1[o] - m1[o] * s;
  } else if (idx < 221312) {
    int o = idx - 221248;
    float s = g2[o] * rsqrtf(v2[o] + 1e-5f);
    bn2[o] = s; bn2[64 + o] = be2[o] - m2[o] * s;
  }
}

#define PACK_HILO8(dst_h, dst_l, src_expr)                                 \
  {                                                                        \
    union { unsigned short us[8]; short8 v; } ph, plo;                     \
    _Pragma("unroll") for (int i = 0; i < 8; ++i) {                        \
      float sv_ = (src_expr);                                              \
      unsigned short h_ = bf16r(sv_);                                      \
      ph.us[i] = h_;                                                       \
      plo.us[i] = bf16r(sv_ - bf2f(h_));                                   \
    }                                                                      \
    *(short8*)(dst_h) = ph.v;                                              \
    *(short8*)(dst_l) = plo.v;                                             \
  }

// ---------------- offset conv via MFMA: 3x3, 64 -> 18 (padded 32) -----------
__global__ __launch_bounds__(256, 4) void conv_off_kernel(
    const float* __restrict__ xin, const unsigned short* __restrict__ wopk,
    const float* __restrict__ boff, float* __restrict__ off) {
  __shared__ __align__(16) unsigned short sb[2][2][64][40];  // [dbuf][part][px][c]
  int tid = threadIdx.x;
  int lane = tid & 63;
  int wave = tid >> 6;
  int px = lane;
  int crow = wave * 8;
  int p0 = blockIdx.x * 64;
  int b = p0 >> 14, hw0 = p0 & 16383;
  int h = hw0 >> 7, w0 = hw0 & 127;
  const float* xb = xin + ((size_t)b << 20);

  floatx4 acc0 = {0.f, 0.f, 0.f, 0.f}, acc1 = {0.f, 0.f, 0.f, 0.f};
  int sA = (wave >> 1) * 2;   // px-subtile pair
  int ot = wave & 1;          // o tile

  int ofs, ofsn; bool ok, okn;
  {
    int yy = h - 1, xx = w0 + px - 1;
    ok = (yy >= 0) & (xx >= 0);
    ofs = (max(yy, 0) << 7) + max(xx, 0);
  }
  float tp0[8], tp1[8];
#pragma unroll
  for (int i = 0; i < 8; ++i) {
    float v = xb[((size_t)(crow + i) << 14) + ofs];
    tp0[i] = ok ? v : 0.f;
  }

#pragma unroll 1
  for (int t = 0; t < 9; ++t) {
    {  // ---- chunk 2t (c 0..31) -> sb[0]
      PACK_HILO8(&sb[0][0][px][crow], &sb[0][1][px][crow], tp0[i]);
#pragma unroll
      for (int i = 0; i < 8; ++i) {  // prefetch c 32..63, same tap
        float v = xb[((size_t)(32 + crow + i) << 14) + ofs];
        tp1[i] = ok ? v : 0.f;
      }
      if (t < 8) {
        int tn = t + 1;
        int yy = h + tn / 3 - 1, xx = w0 + px + tn % 3 - 1;
        okn = (yy >= 0) & (yy < 128) & (xx >= 0) & (xx < 128);
        ofsn = (min(max(yy, 0), 127) << 7) + min(max(xx, 0), 127);
      }
      __syncthreads();
      const unsigned short* ab = wopk + ((size_t)(2 * t) * 2 + ot) * 1024 + lane * 8;
      const short8 ah = *(const short8*)ab;
      const short8 al = *(const short8*)(ab + 512);
      short8 bh0 = *(const short8*)&sb[0][0][sA * 16 + (lane & 15)][(lane >> 4) * 8];
      short8 bl0 = *(const short8*)&sb[0][1][sA * 16 + (lane & 15)][(lane >> 4) * 8];
      acc0 = __builtin_amdgcn_mfma_f32_16x16x32_bf16(ah, bh0, acc0, 0, 0, 0);
      acc0 = __builtin_amdgcn_mfma_f32_16x16x32_bf16(ah, bl0, acc0, 0, 0, 0);
      acc0 = __builtin_amdgcn_mfma_f32_16x16x32_bf16(al, bh0, acc0, 0, 0, 0);
      short8 bh1 = *(const short8*)&sb[0][0][(sA + 1) * 16 + (lane & 15)][(lane >> 4) * 8];
      short8 bl1 = *(const short8*)&sb[0][1][(sA + 1) * 16 + (lane & 15)][(lane >> 4) * 8];
      acc1 = __builtin_amdgcn_mfma_f32_16x16x32_bf16(ah, bh1, acc1, 0, 0, 0);
      acc1 = __builtin_amdgcn_mfma_f32_16x16x32_bf16(ah, bl1, acc1, 0, 0, 0);
      acc1 = __builtin_amdgcn_mfma_f32_16x16x32_bf16(al, bh1, acc1, 0, 0, 0);
    }
    {  // ---- chunk 2t+1 (c 32..63) -> sb[1]
      PACK_HILO8(&sb[1][0][px][crow], &sb[1][1][px][crow], tp1[i]);
      if (t < 8) {
#pragma unroll
        for (int i = 0; i < 8; ++i) {  // prefetch next tap, c 0..31
          float v = xb[((size_t)(crow + i) << 14) + ofsn];
          tp0[i] = okn ? v : 0.f;
        }
      }
      __syncthreads();
      const unsigned short* ab = wopk + ((size_t)(2 * t + 1) * 2 + ot) * 1024 + lane * 8;
      const short8 ah = *(const short8*)ab;
      const short8 al = *(const short8*)(ab + 512);
      short8 bh0 = *(const short8*)&sb[1][0][sA * 16 + (lane & 15)][(lane >> 4) * 8];
      short8 bl0 = *(const short8*)&sb[1][1][sA * 16 + (lane & 15)][(lane >> 4) * 8];
      acc0 = __builtin_amdgcn_mfma_f32_16x16x32_bf16(ah, bh0, acc0, 0, 0, 0);
      acc0 = __builtin_amdgcn_mfma_f32_16x16x32_bf16(ah, bl0, acc0, 0, 0, 0);
      acc0 = __builtin_amdgcn_mfma_f32_16x16x32_bf16(al, bh0, acc0, 0, 0, 0);
      short8 bh1 = *(const short8*)&sb[1][0][(sA + 1) * 16 + (lane & 15)][(lane >> 4) * 8];
      short8 bl1 = *(const short8*)&sb[1][1][(sA + 1) * 16 + (lane & 15)][(lane >> 4) * 8];
      acc1 = __builtin_amdgcn_mfma_f32_16x16x32_bf16(ah, bh1, acc1, 0, 0, 0);
      acc1 = __builtin_amdgcn_mfma_f32_16x16x32_bf16(ah, bl1, acc1, 0, 0, 0);
      acc1 = __builtin_amdgcn_mfma_f32_16x16x32_bf16(al, bh1, acc1, 0, 0, 0);
      ofs = ofsn; ok = okn;
    }
  }
  int q = lane >> 4, nn = lane & 15;
#pragma unroll
  for (int si = 0; si < 2; ++si) {
    floatx4 a = si ? acc1 : acc0;
    int pxc = (sA + si) * 16 + nn;
#pragma unroll
    for (int r = 0; r < 4; ++r) {
      int o = ot * 16 + q * 4 + r;
      if (o < 18)
        off[((size_t)(b * 18 + o) << 14) + hw0 + pxc] = a[r] + boff[o];
    }
  }
}

// ---------------- dcn: sample -> split-bf16 S in LDS -> MFMA -> BN+ReLU -----
// Block = 64 o x 32 px. Thread: 4 c x 4 taps per chunk (tp[16], no dbuf).
__global__ __launch_bounds__(256, 4) void dcn_main_kernel(
    const float* __restrict__ xin, const float* __restrict__ off,
    const unsigned short* __restrict__ wpk, const float* __restrict__ bn,
    float* __restrict__ out) {
  __shared__ __align__(16) unsigned short sb[2][2][32][40];
  int tid = threadIdx.x;
  int lane = tid & 63;
  int wave = tid >> 6;
  int pxl = lane & 31;
  int csub = (wave * 2 + (lane >> 5)) * 4;   // 0,4,...,28 within chunk
  int p0 = blockIdx.x * 32;
  int b = p0 >> 14, hw0 = p0 & 16383;
  int h = hw0 >> 7, w0 = hw0 & 127;
  const float* xb = xin + ((size_t)b << 20);
  const float* offp = off + ((size_t)(b * 18) << 14) + hw0 + pxl;

  floatx4 acc[2] = {{0.f,0.f,0.f,0.f},{0.f,0.f,0.f,0.f}};

  float pw[4], pwn[4] = {0.f, 0.f, 0.f, 0.f};
  int pidx[4], pidxn[4] = {0, 0, 0, 0};

  auto prm_math = [&](int k, float dy, float dx, float* w4, int* i4) {
    float py = (float)(h + k / 3 - 1) + dy;
    float pxf = (float)(w0 + pxl + (k % 3) - 1) + dx;
    float y0f = floorf(py), x0f = floorf(pxf);
    float wy1 = py - y0f, wx1 = pxf - x0f;
    float wy0 = 1.f - wy1, wx0 = 1.f - wx1;
    int y0 = (int)y0f, x0 = (int)x0f;
    int y1 = y0 + 1, x1 = x0 + 1;
    bool vy0 = (y0 >= 0) && (y0 <= 127);
    bool vy1 = (y1 >= 0) && (y1 <= 127);
    bool vx0 = (x0 >= 0) && (x0 <= 127);
    bool vx1 = (x1 >= 0) && (x1 <= 127);
    w4[0] = (vy0 && vx0) ? wy0 * wx0 : 0.f;
    w4[1] = (vy0 && vx1) ? wy0 * wx1 : 0.f;
    w4[2] = (vy1 && vx0) ? wy1 * wx0 : 0.f;
    w4[3] = (vy1 && vx1) ? wy1 * wx1 : 0.f;
    int y0c = min(max(y0, 0), 127), y1c = min(max(y1, 0), 127);
    int x0c = min(max(x0, 0), 127), x1c = min(max(x1, 0), 127);
    i4[0] = (y0c << 7) + x0c;
    i4[1] = (y0c << 7) + x1c;
    i4[2] = (y1c << 7) + x0c;
    i4[3] = (y1c << 7) + x1c;
  };

  {
    float dy = offp[0];
    float dx = offp[(size_t)1 << 14];
    prm_math(0, dy, dx, pw, pidx);
  }
  float dyn = 0.f, dxn = 0.f;

#pragma unroll 1
  for (int chunk = 0; chunk < 18; ++chunk) {
    int k = chunk >> 1, half = chunk & 1;
    // taps for this chunk: 4 c-planes x 4 taps
    float tp[16];
    const float* xc = xb + ((size_t)((half << 5) + csub) << 14);
#pragma unroll
    for (int i = 0; i < 4; ++i) {
      const float* xp = xc + ((size_t)i << 14);
      tp[i * 4 + 0] = xp[pidx[0]]; tp[i * 4 + 1] = xp[pidx[1]];
      tp[i * 4 + 2] = xp[pidx[2]]; tp[i * 4 + 3] = xp[pidx[3]];
    }
    // pipeline the next-k offset load / param math under the tap latency
    if (half == 0 && k < 8) {
      dyn = offp[(size_t)(2 * k + 2) << 14];
      dxn = offp[(size_t)(2 * k + 3) << 14];
    }
    if (half == 1 && k < 8) prm_math(k + 1, dyn, dxn, pwn, pidxn);
    // blend + split-bf16 pack -> LDS
    union { unsigned short us[4]; short4v v; } ph, plo;
#pragma unroll
    for (int i = 0; i < 4; ++i) {
      float sv = fmaf(pw[0], tp[i * 4], fmaf(pw[1], tp[i * 4 + 1],
                 fmaf(pw[2], tp[i * 4 + 2], pw[3] * tp[i * 4 + 3])));
      unsigned short hv = bf16r(sv);
      ph.us[i] = hv;
      plo.us[i] = bf16r(sv - bf2f(hv));
    }
    *(short4v*)&sb[half][0][pxl][csub] = ph.v;
    *(short4v*)&sb[half][1][pxl][csub] = plo.v;
    __syncthreads();
    const unsigned short* ab = wpk + (size_t)(chunk * 4 + wave) * 1024 + lane * 8;
    const short8 ah = *(const short8*)ab;
    const short8 al = *(const short8*)(ab + 512);
#pragma unroll
    for (int s = 0; s < 2; ++s) {
      short8 bh = *(const short8*)&sb[half][0][s * 16 + (lane & 15)][(lane >> 4) * 8];
      short8 bl = *(const short8*)&sb[half][1][s * 16 + (lane & 15)][(lane >> 4) * 8];
      acc[s] = __builtin_amdgcn_mfma_f32_16x16x32_bf16(ah, bh, acc[s], 0, 0, 0);
      acc[s] = __builtin_amdgcn_mfma_f32_16x16x32_bf16(ah, bl, acc[s], 0, 0, 0);
      acc[s] = __builtin_amdgcn_mfma_f32_16x16x32_bf16(al, bh, acc[s], 0, 0, 0);
    }
    if (half == 1 && k < 8) {
#pragma unroll
      for (int q = 0; q < 4; ++q) { pw[q] = pwn[q]; pidx[q] = pidxn[q]; }
    }
  }

  // epilogue: C/D frag row=(lane>>4)*4+r (o), col=lane&15 (px)
  int q = lane >> 4, nn = lane & 15;
#pragma unroll
  for (int s = 0; s < 2; ++s) {
#pragma unroll
    for (int r = 0; r < 4; ++r) {
      int o = wave * 16 + q * 4 + r;
      float val = fmaf(acc[s][r], bn[o], bn[64 + o]);
      out[((size_t)(b * 64 + o) << 14) + hw0 + s * 16 + nn] = fmaxf(val, 0.f);
    }
  }
}

extern "C" void kernel_launch(void* const* d_in, const int* in_sizes, int n_in,
                              void* d_out, int out_size, void* d_ws, size_t ws_size,
                              hipStream_t stream) {
  const float* x      = (const float*)d_in[0];
  const float* w_off1 = (const float*)d_in[1];
  const float* b_off1 = (const float*)d_in[2];
  const float* w1     = (const float*)d_in[3];
  const float* g1     = (const float*)d_in[4];
  const float* be1    = (const float*)d_in[5];
  const float* m1     = (const float*)d_in[6];
  const float* v1     = (const float*)d_in[7];
  const float* w_off2 = (const float*)d_in[8];
  const float* b_off2 = (const float*)d_in[9];
  const float* w2     = (const float*)d_in[10];
  const float* g2     = (const float*)d_in[11];
  const float* be2    = (const float*)d_in[12];
  const float* m2     = (const float*)d_in[13];
  const float* v2     = (const float*)d_in[14];
  float* out = (float*)d_out;

  unsigned short* wpk1  = (unsigned short*)d_ws;          // 73728
  unsigned short* wpk2  = wpk1 + 73728;                   // 73728
  unsigned short* wopk1 = wpk2 + 73728;                   // 36864
  unsigned short* wopk2 = wopk1 + 36864;                  // 36864
  float* bn1  = (float*)(wopk2 + 36864);                  // 128
  float* bn2  = bn1 + 128;                                // 128
  float* offb = bn2 + 128;                                // 4*18*16384
  float* hbuf = offb + 4 * 18 * 16384;                    // 4*64*16384

  prep_kernel<<<865, 256, 0, stream>>>(w1, w2, w_off1, w_off2,
                                       g1, be1, m1, v1, g2, be2, m2, v2,
                                       wpk1, wpk2, wopk1, wopk2, bn1, bn2);

  conv_off_kernel<<<1024, 256, 0, stream>>>(x, wopk1, b_off1, offb);
  dcn_main_kernel<<<2048, 256, 0, stream>>>(x, offb, wpk1, bn1, hbuf);

  conv_off_kernel<<<1024, 256, 0, stream>>>(hbuf, wopk2, b_off2, offb);
  dcn_main_kernel<<<2048, 256, 0, stream>>>(hbuf, offb, wpk2, bn2, out);
}